// Round 18
// baseline (6252.510 us; speedup 1.0000x reference)
//
#include <hip/hip_runtime.h>

#define B 128
#define T 1500
#define NI 80        // N_MELS
#define H 128        // HIDDEN
#define G 384        // 3*H
#define GT 64        // gemm g-tile
#define NTT 128      // gemm t-tile
#define SB 8         // scan blocks
#define NB 16        // batches per scan block

typedef float v2f __attribute__((ext_vector_type(2)));
typedef float f32x4 __attribute__((ext_vector_type(4)));
typedef short s16x8 __attribute__((ext_vector_type(8)));
typedef unsigned short u16x4 __attribute__((ext_vector_type(4)));

__device__ __forceinline__ float sigf(float x) { return 1.0f / (1.0f + __expf(-x)); }
__device__ __forceinline__ float tanhfast(float x) { return 1.0f - 2.0f / (1.0f + __expf(2.0f * x)); }
__device__ __forceinline__ v2f pkfma(v2f a, v2f b, v2f c) { return __builtin_elementwise_fma(a, b, c); }

__device__ __forceinline__ unsigned short f2bf(float f) {
    unsigned int u = __builtin_bit_cast(unsigned int, f);
    unsigned int r = (u + 0x7FFFu + ((u >> 16) & 1u)) >> 16;   // RNE
    return (unsigned short)r;
}
__device__ __forceinline__ float bf2f(unsigned short h) {
    unsigned int u = ((unsigned int)h) << 16;
    return __builtin_bit_cast(float, u);
}

// (lane,e) -> k map used consistently for BOTH A (W) and B (h) fragments.
// k = kt*32 + (lane>>4)*4 + (e&3) + 16*(e>>2). Bijective over k in [0,32) per kt.
// Row map A: row = lane&15; Col map B: col = lane&15 (matches verified C-layout).

// ---------- W_hh fragment setup: fp32 [384][128] -> bf16 hi/lo frags ----------
// frag F(w,i,kt) = (w*6+i)*4+kt ; shorts at ((F*2+s)*64+lane)*8, e ascending.
__global__ __launch_bounds__(256)
void wfrag_kernel(const float* __restrict__ w_hh, unsigned short* __restrict__ wf) {
    int idx = blockIdx.x * 256 + threadIdx.x;     // 24 blocks * 256 = 6144 = 4w*6i*4kt*64lane
    int lane = idx & 63;
    int kt = (idx >> 6) & 3;
    int rest = idx >> 8;                          // 0..23
    int w = rest / 6;
    int i = rest % 6;
    int m = w + 4 * i;
    int grow = 16 * m + (lane & 15);
    int kbase = kt * 32 + ((lane >> 4) << 2);
    unsigned short hi8[8], lo8[8];
#pragma unroll
    for (int e = 0; e < 8; ++e) {
        int k = kbase + (e & 3) + ((e >> 2) << 4);
        float v = w_hh[(size_t)grow * H + k];
        unsigned short h = f2bf(v);
        float rem = v - bf2f(h);
        lo8[e] = f2bf(rem);
        hi8[e] = h;
    }
    int F = idx >> 6;
    unsigned short* dhi = wf + ((size_t)(F * 2 + 0) * 64 + lane) * 8;
    unsigned short* dlo = wf + ((size_t)(F * 2 + 1) * 64 + lane) * 8;
#pragma unroll
    for (int e = 0; e < 8; ++e) { dhi[e] = hi8[e]; dlo[e] = lo8[e]; }
}

// ---------- fused kernel: scan role (blocks 0..7) + gemm role (rest) ----------
__global__ __launch_bounds__(256)
__attribute__((amdgpu_waves_per_eu(1, 1)))
void fused_kernel(const float* __restrict__ x,
                  const float* __restrict__ w_ih, const float* __restrict__ b_ih,
                  const float* __restrict__ gx_read, int ct_read, int first, int last,
                  float* __restrict__ gx_write, int t0_write, int ct_write,
                  const unsigned short* __restrict__ wfrag,
                  const float* __restrict__ b_hh, float* __restrict__ h_state,
                  const float* __restrict__ w_ih_b, const float* __restrict__ b_ih_b,
                  const float* __restrict__ b_hh_b,
                  const float* __restrict__ w1, const float* __restrict__ b1,
                  const float* __restrict__ w2, const float* __restrict__ b2,
                  float* __restrict__ out) {
    // gemm-role LDS
    __shared__ __align__(16) float wT[80][GT + 2];
    __shared__ __align__(16) float xT[80][NTT + 4];
    __shared__ float bias_s[GT];
    // scan-role LDS
    __shared__ __align__(16) unsigned short HT[2][2][NB][136];  // dbuf x split x batch x k(+pad)
    __shared__ __align__(16) float hf[NB][H];
    __shared__ __align__(16) float tail_gx[G];
    __shared__ __align__(16) float last_s[2 * H];
    __shared__ __align__(16) float xb_s[NI];

    int tid = threadIdx.x;
    int scanBlocks = (ct_read > 0) ? SB : 0;

    if ((int)blockIdx.x < scanBlocks) {
        // ================= SCAN ROLE (MFMA, 16 batches) =================
        int sb = blockIdx.x;
        int ct = ct_read;
        int w = tid >> 6;
        int lane = tid & 63;
        int lg = (lane >> 4);
        int bcol = lane & 15;
        int bg = sb * NB + bcol;
        int jA = 16 * w + 4 * lg;       // + reg
        int jB = jA + 64;

        // A-frags (static): slots i=0..5 -> tiles m = w+4i (r:jA, r:jB, z:jA, z:jB, n:jA, n:jB)
        s16x8 WA[6][4][2];
        {
            const s16x8* wf8 = (const s16x8*)wfrag;
#pragma unroll
            for (int i = 0; i < 6; ++i)
#pragma unroll
                for (int kt = 0; kt < 4; ++kt)
#pragma unroll
                    for (int s = 0; s < 2; ++s) {
                        int F = (w * 6 + i) * 4 + kt;
                        WA[i][kt][s] = wf8[(size_t)(F * 2 + s) * 64 + lane];
                    }
        }
        // biases
        float brA[4], bzA[4], bnA[4], brB[4], bzB[4], bnB[4];
#pragma unroll
        for (int r = 0; r < 4; ++r) {
            brA[r] = b_hh[jA + r];       bzA[r] = b_hh[128 + jA + r]; bnA[r] = b_hh[256 + jA + r];
            brB[r] = b_hh[jB + r];       bzB[r] = b_hh[128 + jB + r]; bnB[r] = b_hh[256 + jB + r];
        }
        // gx gather offsets: slot i, reg r -> g = 16*m_i + 4*lg + r
        int goff[6][4];
#pragma unroll
        for (int i = 0; i < 6; ++i) {
            int m = w + 4 * i;
#pragma unroll
            for (int r = 0; r < 4; ++r) {
                int g = 16 * m + 4 * lg + r;
                goff[i][r] = (bg * G + g) * ct;
            }
        }
        // h state in-lane
        float hA[4], hB[4];
#pragma unroll
        for (int r = 0; r < 4; ++r) {
            hA[r] = first ? 0.f : h_state[bg * H + jA + r];
            hB[r] = first ? 0.f : h_state[bg * H + jB + r];
        }
        // seed HT[0]
        {
            unsigned short a0[4], a1[4], b0[4], b1v[4];
#pragma unroll
            for (int r = 0; r < 4; ++r) {
                unsigned short hh = f2bf(hA[r]); a0[r] = hh; a1[r] = f2bf(hA[r] - bf2f(hh));
                unsigned short hg = f2bf(hB[r]); b0[r] = hg; b1v[r] = f2bf(hB[r] - bf2f(hg));
            }
            *(u16x4*)&HT[0][0][bcol][jA] = u16x4{a0[0], a0[1], a0[2], a0[3]};
            *(u16x4*)&HT[0][1][bcol][jA] = u16x4{a1[0], a1[1], a1[2], a1[3]};
            *(u16x4*)&HT[0][0][bcol][jB] = u16x4{b0[0], b0[1], b0[2], b0[3]};
            *(u16x4*)&HT[0][1][bcol][jB] = u16x4{b1v[0], b1v[1], b1v[2], b1v[3]};
        }
        // preload gx for t=0
        float GXc[24];
#pragma unroll
        for (int i = 0; i < 6; ++i)
#pragma unroll
            for (int r = 0; r < 4; ++r) GXc[i * 4 + r] = gx_read[(size_t)goff[i][r] + 0];
        __syncthreads();

        for (int t = 0; t < ct; ++t) {
            int buf = t & 1;
            // B-frags from HT[buf]
            s16x8 Bhi[4], Blo[4];
#pragma unroll
            for (int kt = 0; kt < 4; ++kt) {
                const u16x4* p0 = (const u16x4*)&HT[buf][0][bcol][kt * 32 + lg * 4];
                u16x4 a = p0[0], b = p0[4];
                Bhi[kt] = s16x8{(short)a.x, (short)a.y, (short)a.z, (short)a.w,
                                (short)b.x, (short)b.y, (short)b.z, (short)b.w};
                const u16x4* p1 = (const u16x4*)&HT[buf][1][bcol][kt * 32 + lg * 4];
                u16x4 c = p1[0], d = p1[4];
                Blo[kt] = s16x8{(short)c.x, (short)c.y, (short)c.z, (short)c.w,
                                (short)d.x, (short)d.y, (short)d.z, (short)d.w};
            }
            // prefetch gx for t+1 (stays in flight across the barrier)
            float GXn[24];
            {
                int tn = (t + 1 < ct) ? (t + 1) : t;
#pragma unroll
                for (int i = 0; i < 6; ++i)
#pragma unroll
                    for (int r = 0; r < 4; ++r) GXn[i * 4 + r] = gx_read[(size_t)goff[i][r] + tn];
            }
            // MFMA: C[i] = W_i * h  (split-bf16: hi*hi + hi*lo + lo*hi)
            f32x4 C[6];
#pragma unroll
            for (int i = 0; i < 6; ++i) C[i] = f32x4{0.f, 0.f, 0.f, 0.f};
#pragma unroll
            for (int kt = 0; kt < 4; ++kt) {
#pragma unroll
                for (int i = 0; i < 6; ++i) {
                    C[i] = __builtin_amdgcn_mfma_f32_16x16x32_bf16(WA[i][kt][0], Bhi[kt], C[i], 0, 0, 0);
                    C[i] = __builtin_amdgcn_mfma_f32_16x16x32_bf16(WA[i][kt][0], Blo[kt], C[i], 0, 0, 0);
                    C[i] = __builtin_amdgcn_mfma_f32_16x16x32_bf16(WA[i][kt][1], Bhi[kt], C[i], 0, 0, 0);
                }
            }
            // gates: 8 cells per lane (jA block: slots 0,2,4; jB block: slots 1,3,5)
#pragma unroll
            for (int r = 0; r < 4; ++r) {
                float rr = sigf(GXc[0 * 4 + r] + brA[r] + C[0][r]);
                float zz = sigf(GXc[2 * 4 + r] + bzA[r] + C[2][r]);
                float nn = tanhfast(GXc[4 * 4 + r] + rr * (C[4][r] + bnA[r]));
                hA[r] = nn + zz * (hA[r] - nn);
                float rb = sigf(GXc[1 * 4 + r] + brB[r] + C[1][r]);
                float zb = sigf(GXc[3 * 4 + r] + bzB[r] + C[3][r]);
                float nb = tanhfast(GXc[5 * 4 + r] + rb * (C[5][r] + bnB[r]));
                hB[r] = nb + zb * (hB[r] - nb);
            }
            // write h(t+1) bf16-split to HT[buf^1]
            {
                unsigned short a0[4], a1[4], b0[4], b1v[4];
#pragma unroll
                for (int r = 0; r < 4; ++r) {
                    unsigned short hh = f2bf(hA[r]); a0[r] = hh; a1[r] = f2bf(hA[r] - bf2f(hh));
                    unsigned short hg = f2bf(hB[r]); b0[r] = hg; b1v[r] = f2bf(hB[r] - bf2f(hg));
                }
                int nb2 = buf ^ 1;
                *(u16x4*)&HT[nb2][0][bcol][jA] = u16x4{a0[0], a0[1], a0[2], a0[3]};
                *(u16x4*)&HT[nb2][1][bcol][jA] = u16x4{a1[0], a1[1], a1[2], a1[3]};
                *(u16x4*)&HT[nb2][0][bcol][jB] = u16x4{b0[0], b0[1], b0[2], b0[3]};
                *(u16x4*)&HT[nb2][1][bcol][jB] = u16x4{b1v[0], b1v[1], b1v[2], b1v[3]};
            }
#pragma unroll
            for (int k = 0; k < 24; ++k) GXc[k] = GXn[k];
            asm volatile("s_waitcnt lgkmcnt(0)\n\ts_barrier" ::: "memory");
        }

        if (!last) {
#pragma unroll
            for (int r = 0; r < 4; ++r) {
                h_state[bg * H + jA + r] = hA[r];
                h_state[bg * H + jB + r] = hB[r];
            }
            return;
        }

        // ---- tail: backward single step (h0=0) + MLP head, per batch ----
#pragma unroll
        for (int r = 0; r < 4; ++r) { hf[bcol][jA + r] = hA[r]; hf[bcol][jB + r] = hB[r]; }
        __syncthreads();

        for (int bb = 0; bb < NB; ++bb) {
            int bgg = sb * NB + bb;
            if (tid < NI) xb_s[tid] = x[((size_t)bgg * T + (T - 1)) * NI + tid];
            __syncthreads();
            for (int gg = tid; gg < G; gg += 256) {
                const float4* wbr = (const float4*)(w_ih_b + (size_t)gg * NI);
                const float4* xv = (const float4*)xb_s;
                float a0 = 0.f, a1 = 0.f, a2 = 0.f, a3 = 0.f;
#pragma unroll
                for (int i = 0; i < 20; ++i) {
                    float4 wv = wbr[i]; float4 x4 = xv[i];
                    a0 = fmaf(wv.x, x4.x, a0); a1 = fmaf(wv.y, x4.y, a1);
                    a2 = fmaf(wv.z, x4.z, a2); a3 = fmaf(wv.w, x4.w, a3);
                }
                tail_gx[gg] = b_ih_b[gg] + ((a0 + a1) + (a2 + a3));
            }
            __syncthreads();
            if (tid < H) {
                float r = sigf(tail_gx[tid] + b_hh_b[tid]);
                float z = sigf(tail_gx[tid + H] + b_hh_b[tid + H]);
                float n = tanhfast(tail_gx[tid + 2 * H] + r * b_hh_b[tid + 2 * H]);
                last_s[H + tid] = (1.f - z) * n;
                last_s[tid] = hf[bb][tid];
            }
            __syncthreads();
            if (tid < 64) {
                const float4* w1r = (const float4*)(w1 + (size_t)tid * 2 * H);
                const float4* lv = (const float4*)last_s;
                float a0 = 0.f, a1 = 0.f, a2 = 0.f, a3 = 0.f;
#pragma unroll
                for (int i = 0; i < 64; ++i) {
                    float4 wv = w1r[i]; float4 l4 = lv[i];
                    a0 = fmaf(wv.x, l4.x, a0); a1 = fmaf(wv.y, l4.y, a1);
                    a2 = fmaf(wv.z, l4.z, a2); a3 = fmaf(wv.w, l4.w, a3);
                }
                float v = b1[tid] + ((a0 + a1) + (a2 + a3));
                v = fmaxf(v, 0.f) * w2[tid];
#pragma unroll
                for (int off = 32; off > 0; off >>= 1) v += __shfl_down(v, off);
                if (tid == 0) out[bgg] = v + b2[0];
            }
            __syncthreads();
        }
        return;
    }

    // ================= GEMM ROLE (r16 v3 body, job-strided) =================
    if (ct_write <= 0) return;
    {
        int ct = ct_write;
        int t0 = t0_write;
        int gb = blockIdx.x - scanBlocks;
        int ngb = gridDim.x - scanBlocks;
        int ttiles = (ct + NTT - 1) / NTT;
        int jobs = ttiles * (G / GT) * B;
        int gi = tid & 15;
        int ti = tid >> 4;

        for (int job = gb; job < jobs; job += ngb) {
            int tile = job % ttiles;
            int rem = job / ttiles;
            int gy = rem % (G / GT);
            int b = rem / (G / GT);
            int g0b = gy * GT;
            int tt0 = tile * NTT;

            __syncthreads();   // protect previous job's LDS
            for (int i = tid; i < GT * 20; i += 256) {
                int g = i & (GT - 1);
                int kc = i >> 6;
                float4 v = *(const float4*)(w_ih + (size_t)(g0b + g) * NI + 4 * kc);
                wT[4 * kc + 0][g] = v.x; wT[4 * kc + 1][g] = v.y;
                wT[4 * kc + 2][g] = v.z; wT[4 * kc + 3][g] = v.w;
            }
            for (int i = tid; i < NTT * 20; i += 256) {
                int c = i & (NTT - 1);
                int kc = i >> 7;
                int tt = tt0 + c; if (tt > ct - 1) tt = ct - 1;
                float4 v = *(const float4*)(x + ((size_t)b * T + (size_t)(t0 + tt)) * NI + 4 * kc);
                xT[4 * kc + 0][c] = v.x; xT[4 * kc + 1][c] = v.y;
                xT[4 * kc + 2][c] = v.z; xT[4 * kc + 3][c] = v.w;
            }
            if (tid < GT) bias_s[tid] = b_ih[g0b + tid];
            __syncthreads();

            v2f acc[4][4];
#pragma unroll
            for (int r = 0; r < 4; ++r)
#pragma unroll
                for (int j = 0; j < 4; ++j) acc[r][j] = v2f{0.f, 0.f};

#pragma unroll 2
            for (int k = 0; k < 80; ++k) {
                const v2f* wv = (const v2f*)&wT[k][4 * gi];
                v2f w01 = wv[0], w23 = wv[1];
                const float4* xv = (const float4*)&xT[k][8 * ti];
                float4 x03 = xv[0], x47 = xv[1];
                v2f xp0 = {x03.x, x03.y}, xp1 = {x03.z, x03.w};
                v2f xp2 = {x47.x, x47.y}, xp3 = {x47.z, x47.w};
                float wr[4] = {w01.x, w01.y, w23.x, w23.y};
#pragma unroll
                for (int r = 0; r < 4; ++r) {
                    v2f ws = {wr[r], wr[r]};
                    acc[r][0] = pkfma(ws, xp0, acc[r][0]);
                    acc[r][1] = pkfma(ws, xp1, acc[r][1]);
                    acc[r][2] = pkfma(ws, xp2, acc[r][2]);
                    acc[r][3] = pkfma(ws, xp3, acc[r][3]);
                }
            }
            __syncthreads();   // xT reads done; reuse as output tile

            float (*ot)[NTT + 4] = (float (*)[NTT + 4])xT;
#pragma unroll
            for (int r = 0; r < 4; ++r) {
                float bias = bias_s[4 * gi + r];
#pragma unroll
                for (int j = 0; j < 4; ++j) {
                    float2 o; o.x = acc[r][j].x + bias; o.y = acc[r][j].y + bias;
                    *(float2*)&ot[4 * gi + r][8 * ti + 2 * j] = o;
                }
            }
            __syncthreads();

            for (int i = tid; i < GT * (NTT / 4); i += 256) {
                int row = i >> 5;
                int col = i & 31;
                int t = tt0 + 4 * col;
                if (t < ct) {
                    float4 v = *(const float4*)&ot[row][4 * col];
                    *(float4*)(gx_write + ((size_t)b * G + g0b + row) * ct + t) = v;
                }
            }
        }
    }
}

extern "C" void kernel_launch(void* const* d_in, const int* in_sizes, int n_in,
                              void* d_out, int out_size, void* d_ws, size_t ws_size,
                              hipStream_t stream) {
    (void)in_sizes; (void)n_in; (void)out_size;
    const float* x      = (const float*)d_in[0];
    const float* w_ih_f = (const float*)d_in[1];
    const float* w_hh_f = (const float*)d_in[2];
    const float* b_ih_f = (const float*)d_in[3];
    const float* b_hh_f = (const float*)d_in[4];
    const float* w_ih_b = (const float*)d_in[5];
    const float* w_hh_b = (const float*)d_in[6];  // unused: h0=0 makes gh_b = b_hh_b
    const float* b_ih_b = (const float*)d_in[7];
    const float* b_hh_b = (const float*)d_in[8];
    const float* w1     = (const float*)d_in[9];
    const float* b1     = (const float*)d_in[10];
    const float* w2     = (const float*)d_in[11];
    const float* b2     = (const float*)d_in[12];
    (void)w_hh_b;
    float* out = (float*)d_out;

    // ws layout: h_state (B*H f32) | wfrag (12288 frags * 16B = 196608B) | buf0 | buf1
    float* h_state = (float*)d_ws;
    unsigned short* wfrag = (unsigned short*)(h_state + B * H);
    float* buf0 = (float*)((char*)wfrag + 196608);
    size_t used = (size_t)B * H * 4 + 196608;
    size_t avail = ws_size > used ? ws_size - used : 0;

    size_t per = (size_t)B * G * sizeof(float);    // bytes per timestep
    long long chunk = 376;
    if (avail < 2 * per * (size_t)chunk) {
        long long c = (long long)(avail / (2 * per)) & ~3LL;
        chunk = c;
    }
    if (chunk > T) chunk = T;
    if (chunk < 4) chunk = 4;
    float* bufs[2] = { buf0, buf0 + (size_t)B * G * (size_t)chunk };

    wfrag_kernel<<<dim3(24), dim3(256), 0, stream>>>(w_hh_f, wfrag);

    // prologue: all blocks gemm chunk 0
    int cs0 = (T < (int)chunk) ? T : (int)chunk;
    fused_kernel<<<dim3(256), dim3(256), 0, stream>>>(
        x, w_ih_f, b_ih_f,
        nullptr, 0, 0, 0,
        bufs[0], 0, cs0,
        wfrag, b_hh_f, h_state,
        w_ih_b, b_ih_b, b_hh_b, w1, b1, w2, b2, out);

    int i = 0;
    for (int t0 = 0; t0 < T; ++i) {
        int cs = (T - t0 < (int)chunk) ? (T - t0) : (int)chunk;
        int nt0 = t0 + cs;
        int csn = (nt0 < T) ? ((T - nt0 < (int)chunk) ? (T - nt0) : (int)chunk) : 0;
        fused_kernel<<<dim3(256), dim3(256), 0, stream>>>(
            x, w_ih_f, b_ih_f,
            bufs[i & 1], cs, (t0 == 0) ? 1 : 0, (nt0 >= T) ? 1 : 0,
            bufs[(i + 1) & 1], nt0, csn,
            wfrag, b_hh_f, h_state,
            w_ih_b, b_ih_b, b_hh_b, w1, b1, w2, b2, out);
        t0 = nt0;
    }
}

// Round 19
// 2617.888 us; speedup vs baseline: 2.3884x; 2.3884x over previous
//
#include <hip/hip_runtime.h>

#define B 128
#define T 1500
#define NI 80
#define H 128
#define G 384
#define GT 64
#define NTT 128
#define SBK 8        // scan blocks
#define NB 16        // batches per scan block
#define RPB 120      // repack blocks

typedef float v2f __attribute__((ext_vector_type(2)));
typedef float f32x4 __attribute__((ext_vector_type(4)));
typedef short s16x8 __attribute__((ext_vector_type(8)));
typedef unsigned short u16x4 __attribute__((ext_vector_type(4)));

__device__ __forceinline__ float sigf(float x) { return 1.0f / (1.0f + __expf(-x)); }
__device__ __forceinline__ float tanhfast(float x) { return 1.0f - 2.0f / (1.0f + __expf(2.0f * x)); }
__device__ __forceinline__ v2f pkfma(v2f a, v2f b, v2f c) { return __builtin_elementwise_fma(a, b, c); }

__device__ __forceinline__ unsigned short f2bf(float f) {
    unsigned int u = __builtin_bit_cast(unsigned int, f);
    unsigned int r = (u + 0x7FFFu + ((u >> 16) & 1u)) >> 16;
    return (unsigned short)r;
}
__device__ __forceinline__ float bf2f(unsigned short h) {
    unsigned int u = ((unsigned int)h) << 16;
    return __builtin_bit_cast(float, u);
}

// ---------- W_hh -> bf16 hi/lo MFMA A-fragments (verified r18) ----------
// tile m 0..23 (row block 16m..16m+15 of [384][128]); F = ((m&3)*6 + (m>>2))*4 + kt
// lane covers row 16m+(lane&15), k = kt*32 + (lane>>4)*4 + (e&3) + 16*(e>>2)
__global__ __launch_bounds__(256)
void wfrag_kernel(const float* __restrict__ w_hh, unsigned short* __restrict__ wf) {
    int idx = blockIdx.x * 256 + threadIdx.x;
    int lane = idx & 63;
    int kt = (idx >> 6) & 3;
    int rest = idx >> 8;
    int w = rest / 6;
    int i = rest % 6;
    int m = w + 4 * i;
    int grow = 16 * m + (lane & 15);
    int kbase = kt * 32 + ((lane >> 4) << 2);
    unsigned short hi8[8], lo8[8];
#pragma unroll
    for (int e = 0; e < 8; ++e) {
        int k = kbase + (e & 3) + ((e >> 2) << 4);
        float v = w_hh[(size_t)grow * H + k];
        unsigned short h = f2bf(v);
        lo8[e] = f2bf(v - bf2f(h));
        hi8[e] = h;
    }
    int F = idx >> 6;
    unsigned short* dhi = wf + ((size_t)(F * 2 + 0) * 64 + lane) * 8;
    unsigned short* dlo = wf + ((size_t)(F * 2 + 1) * 64 + lane) * 8;
#pragma unroll
    for (int e = 0; e < 8; ++e) { dhi[e] = hi8[e]; dlo[e] = lo8[e]; }
}

// frag-layout gx: float at ((((sb*8+w)*ct + t)*64 + lane)*12 + gt*4 + r)
// where lane = lg*16 + bcol, g-row = gt*128 + 64*(w>>2) + 16*(w&3) + 4*lg + r.

__global__ __launch_bounds__(512)
__attribute__((amdgpu_waves_per_eu(2, 2)))
void fused_kernel(const float* __restrict__ x,
                  const float* __restrict__ w_ih, const float* __restrict__ b_ih,
                  const float* __restrict__ gx3_rd, int ct_scan, int first, int last,
                  const float* __restrict__ raw_rp, float* __restrict__ gx3_wr, int ct_rp,
                  float* __restrict__ raw_gm, int t0_gm, int ct_gm,
                  const unsigned short* __restrict__ wfrag,
                  const float* __restrict__ b_hh, float* __restrict__ h_state,
                  const float* __restrict__ w_ih_b, const float* __restrict__ b_ih_b,
                  const float* __restrict__ b_hh_b,
                  const float* __restrict__ w1, const float* __restrict__ b1,
                  const float* __restrict__ w2, const float* __restrict__ b2,
                  float* __restrict__ out) {
    // gemm LDS
    __shared__ __align__(16) float wT[80][GT + 2];
    __shared__ __align__(16) float xT[80][NTT + 4];
    __shared__ float bias_s[GT];
    // scan LDS
    __shared__ __align__(16) unsigned short HT[2][2][NB][136];
    __shared__ __align__(16) float hf[NB][H];
    __shared__ __align__(16) float tail_gx[G];
    __shared__ __align__(16) float last_s[2 * H];
    __shared__ __align__(16) float xb_s[NI];
    // repack LDS
    __shared__ __align__(16) float ls[32][16][12];

    int tid = threadIdx.x;
    int nscan = (ct_scan > 0) ? SBK : 0;
    int nrp = (ct_rp > 0) ? RPB : 0;

    if ((int)blockIdx.x < nscan) {
        // ===================== SCAN (MFMA, 16 batches, 8 waves) =====================
        int sb = blockIdx.x;
        int ct = ct_scan;
        int w = tid >> 6;              // 0..7
        int lane = tid & 63;
        int lg = lane >> 4;
        int bcol = lane & 15;
        int bg = sb * NB + bcol;
        int J0 = 64 * (w >> 2) + 16 * (w & 3);
        int jlo = J0 + 4 * lg;         // + reg

        // A-frags: gate gt 0..2 -> tile m = gt*8 + (w&3) + 4*(w>>2)
        s16x8 WA[3][4][2];
        {
            const s16x8* wf8 = (const s16x8*)wfrag;
#pragma unroll
            for (int gt = 0; gt < 3; ++gt) {
                int m = gt * 8 + (w & 3) + 4 * (w >> 2);
                int Fb = ((m & 3) * 6 + (m >> 2)) * 4;
#pragma unroll
                for (int kt = 0; kt < 4; ++kt)
#pragma unroll
                    for (int s = 0; s < 2; ++s)
                        WA[gt][kt][s] = wf8[(size_t)((Fb + kt) * 2 + s) * 64 + lane];
            }
        }
        float bR[4], bZ[4], bN[4];
#pragma unroll
        for (int r = 0; r < 4; ++r) {
            bR[r] = b_hh[jlo + r];
            bZ[r] = b_hh[128 + jlo + r];
            bN[r] = b_hh[256 + jlo + r];
        }
        float hc[4];
#pragma unroll
        for (int r = 0; r < 4; ++r) hc[r] = first ? 0.f : h_state[bg * H + jlo + r];
        // seed HT[0] (each (w,lg,bcol) writes its 4 j's; waves 4..7 duplicate waves 0..3's
        // j range? No: J0 for w and w+4 differ (64 offset) -> all 128 j covered once.)
        {
            unsigned short a0[4], a1[4];
#pragma unroll
            for (int r = 0; r < 4; ++r) {
                unsigned short hh = f2bf(hc[r]);
                a0[r] = hh; a1[r] = f2bf(hc[r] - bf2f(hh));
            }
            *(u16x4*)&HT[0][0][bcol][jlo] = u16x4{a0[0], a0[1], a0[2], a0[3]};
            *(u16x4*)&HT[0][1][bcol][jlo] = u16x4{a1[0], a1[1], a1[2], a1[3]};
        }
        // gx base for this (sb, w, lane)
        const float* gbase = gx3_rd + ((size_t)(sb * 8 + w) * ct * 64 + lane) * 12;
        f32x4 Gc[3], Gn[3];
#pragma unroll
        for (int gt = 0; gt < 3; ++gt) Gc[gt] = *(const f32x4*)(gbase + (size_t)0 * 64 * 12 + gt * 4);
        __syncthreads();

        for (int t = 0; t < ct; ++t) {
            int buf = t & 1;
            s16x8 Bhi[4], Blo[4];
#pragma unroll
            for (int kt = 0; kt < 4; ++kt) {
                const u16x4* p0 = (const u16x4*)&HT[buf][0][bcol][kt * 32 + lg * 4];
                u16x4 a = p0[0], b = p0[4];
                Bhi[kt] = s16x8{(short)a.x, (short)a.y, (short)a.z, (short)a.w,
                                (short)b.x, (short)b.y, (short)b.z, (short)b.w};
                const u16x4* p1 = (const u16x4*)&HT[buf][1][bcol][kt * 32 + lg * 4];
                u16x4 c = p1[0], d = p1[4];
                Blo[kt] = s16x8{(short)c.x, (short)c.y, (short)c.z, (short)c.w,
                                (short)d.x, (short)d.y, (short)d.z, (short)d.w};
            }
            {
                int tn = (t + 1 < ct) ? (t + 1) : t;
#pragma unroll
                for (int gt = 0; gt < 3; ++gt)
                    Gn[gt] = *(const f32x4*)(gbase + (size_t)tn * 64 * 12 + gt * 4);
            }
            f32x4 C[3];
#pragma unroll
            for (int gt = 0; gt < 3; ++gt) C[gt] = f32x4{0.f, 0.f, 0.f, 0.f};
#pragma unroll
            for (int kt = 0; kt < 4; ++kt)
#pragma unroll
                for (int gt = 0; gt < 3; ++gt) {
                    C[gt] = __builtin_amdgcn_mfma_f32_16x16x32_bf16(WA[gt][kt][0], Bhi[kt], C[gt], 0, 0, 0);
                    C[gt] = __builtin_amdgcn_mfma_f32_16x16x32_bf16(WA[gt][kt][0], Blo[kt], C[gt], 0, 0, 0);
                    C[gt] = __builtin_amdgcn_mfma_f32_16x16x32_bf16(WA[gt][kt][1], Bhi[kt], C[gt], 0, 0, 0);
                }
#pragma unroll
            for (int r = 0; r < 4; ++r) {
                float rr = sigf(Gc[0][r] + bR[r] + C[0][r]);
                float zz = sigf(Gc[1][r] + bZ[r] + C[1][r]);
                float nn = tanhfast(Gc[2][r] + rr * (C[2][r] + bN[r]));
                hc[r] = nn + zz * (hc[r] - nn);
            }
            {
                unsigned short a0[4], a1[4];
#pragma unroll
                for (int r = 0; r < 4; ++r) {
                    unsigned short hh = f2bf(hc[r]);
                    a0[r] = hh; a1[r] = f2bf(hc[r] - bf2f(hh));
                }
                int nb2 = buf ^ 1;
                *(u16x4*)&HT[nb2][0][bcol][jlo] = u16x4{a0[0], a0[1], a0[2], a0[3]};
                *(u16x4*)&HT[nb2][1][bcol][jlo] = u16x4{a1[0], a1[1], a1[2], a1[3]};
            }
#pragma unroll
            for (int gt = 0; gt < 3; ++gt) Gc[gt] = Gn[gt];
            asm volatile("s_waitcnt lgkmcnt(0)\n\ts_barrier" ::: "memory");
        }

        if (!last) {
#pragma unroll
            for (int r = 0; r < 4; ++r) h_state[bg * H + jlo + r] = hc[r];
            return;
        }

        // ---- tail: backward single step (h0=0) + MLP head, per batch ----
#pragma unroll
        for (int r = 0; r < 4; ++r) hf[bcol][jlo + r] = hc[r];
        __syncthreads();

        for (int bb = 0; bb < NB; ++bb) {
            int bgg = sb * NB + bb;
            if (tid < NI) xb_s[tid] = x[((size_t)bgg * T + (T - 1)) * NI + tid];
            __syncthreads();
            if (tid < G) {
                const float4* wbr = (const float4*)(w_ih_b + (size_t)tid * NI);
                const float4* xv = (const float4*)xb_s;
                float a0 = 0.f, a1 = 0.f, a2 = 0.f, a3 = 0.f;
#pragma unroll
                for (int i = 0; i < 20; ++i) {
                    float4 wv = wbr[i]; float4 x4 = xv[i];
                    a0 = fmaf(wv.x, x4.x, a0); a1 = fmaf(wv.y, x4.y, a1);
                    a2 = fmaf(wv.z, x4.z, a2); a3 = fmaf(wv.w, x4.w, a3);
                }
                tail_gx[tid] = b_ih_b[tid] + ((a0 + a1) + (a2 + a3));
            }
            __syncthreads();
            if (tid < H) {
                float r = sigf(tail_gx[tid] + b_hh_b[tid]);
                float z = sigf(tail_gx[tid + H] + b_hh_b[tid + H]);
                float n = tanhfast(tail_gx[tid + 2 * H] + r * b_hh_b[tid + 2 * H]);
                last_s[H + tid] = (1.f - z) * n;
                last_s[tid] = hf[bb][tid];
            }
            __syncthreads();
            if (tid < 64) {
                const float4* w1r = (const float4*)(w1 + (size_t)tid * 2 * H);
                const float4* lv = (const float4*)last_s;
                float a0 = 0.f, a1 = 0.f, a2 = 0.f, a3 = 0.f;
#pragma unroll
                for (int i = 0; i < 64; ++i) {
                    float4 wv = w1r[i]; float4 l4 = lv[i];
                    a0 = fmaf(wv.x, l4.x, a0); a1 = fmaf(wv.y, l4.y, a1);
                    a2 = fmaf(wv.z, l4.z, a2); a3 = fmaf(wv.w, l4.w, a3);
                }
                float v = b1[tid] + ((a0 + a1) + (a2 + a3));
                v = fmaxf(v, 0.f) * w2[tid];
#pragma unroll
                for (int off = 32; off > 0; off >>= 1) v += __shfl_down(v, off);
                if (tid == 0) out[bgg] = v + b2[0];
            }
            __syncthreads();
        }
        return;
    }

    if ((int)blockIdx.x < nscan + nrp) {
        // ===================== REPACK: raw [b][g][t] -> frag layout =====================
        int rb = blockIdx.x - nscan;
        int ct = ct_rp;
        int ntw = (ct + 31) / 32;
        int jobs = 8 * 8 * 4 * ntw;    // sb, w, lg, tw
        for (int job = rb; job < jobs; job += nrp) {
            int tw = job % ntw;
            int rest = job / ntw;
            int lg = rest & 3;
            int w = (rest >> 2) & 7;
            int sb = rest >> 5;
            __syncthreads();   // protect previous job's ls
            if (tid < 384) {
                int r = tid & 3;
                int b = (tid >> 2) & 15;
                int tq2 = (tid >> 6) & 1;
                int gt = tid >> 7;                         // 0..2
                int g = gt * 128 + 64 * (w >> 2) + 16 * (w & 3) + 4 * lg + r;
                const float* row = raw_rp + ((size_t)(sb * 16 + b) * G + g) * ct;
                int e = gt * 4 + r;
#pragma unroll
                for (int q4 = 0; q4 < 4; ++q4) {
                    int toff = tw * 32 + tq2 * 16 + q4 * 4;
                    if (toff < ct) {
                        float4 v = *(const float4*)(row + toff);
                        int tt = tq2 * 16 + q4 * 4;
                        ls[tt + 0][b][e] = v.x; ls[tt + 1][b][e] = v.y;
                        ls[tt + 2][b][e] = v.z; ls[tt + 3][b][e] = v.w;
                    }
                }
            }
            __syncthreads();
            // write out: per tt, 16 lanes x 12 e = 192 floats = 48 float4, contiguous
            for (int it = tid; it < 32 * 48; it += 512) {
                int tt = it / 48;
                int f4 = it % 48;
                int t = tw * 32 + tt;
                if (t < ct) {
                    float4 v = ((const float4*)&ls[tt][0][0])[f4];
                    size_t dst = (((size_t)(sb * 8 + w) * ct + t) * 64 + lg * 16) * 12 + f4 * 4;
                    *(float4*)(gx3_wr + dst) = v;
                }
            }
        }
        return;
    }

    // ===================== GEMM (r17-proven 512-thread job loop) =====================
    if (ct_gm <= 0) return;
    {
        int ct = ct_gm;
        int t0 = t0_gm;
        int gb = blockIdx.x - nscan - nrp;
        int ngb = gridDim.x - nscan - nrp;
        int ttiles = (ct + NTT - 1) / NTT;
        int jobs = ttiles * (G / GT) * B;
        int gi = tid & 15;
        int ti = (tid & 255) >> 4;     // 0..15 (two half-blocks duplicate? no:)
        // use full 512 threads: 16 gi x 32 tj -> thread computes 4g x 4t
        int tj = tid >> 4;             // 0..31

        for (int job = gb; job < jobs; job += ngb) {
            int tile = job % ttiles;
            int rem = job / ttiles;
            int gy = rem % (G / GT);
            int b = rem / (G / GT);
            int g0b = gy * GT;
            int tt0 = tile * NTT;

            __syncthreads();
            for (int i = tid; i < GT * 20; i += 512) {
                int g = i & (GT - 1);
                int kc = i >> 6;
                float4 v = *(const float4*)(w_ih + (size_t)(g0b + g) * NI + 4 * kc);
                wT[4 * kc + 0][g] = v.x; wT[4 * kc + 1][g] = v.y;
                wT[4 * kc + 2][g] = v.z; wT[4 * kc + 3][g] = v.w;
            }
            for (int i = tid; i < NTT * 20; i += 512) {
                int c = i & (NTT - 1);
                int kc = i >> 7;
                int tt = tt0 + c; if (tt > ct - 1) tt = ct - 1;
                float4 v = *(const float4*)(x + ((size_t)b * T + (size_t)(t0 + tt)) * NI + 4 * kc);
                xT[4 * kc + 0][c] = v.x; xT[4 * kc + 1][c] = v.y;
                xT[4 * kc + 2][c] = v.z; xT[4 * kc + 3][c] = v.w;
            }
            if (tid < GT) bias_s[tid] = b_ih[tid + g0b];
            __syncthreads();

            v2f acc[4][2];
#pragma unroll
            for (int r = 0; r < 4; ++r) { acc[r][0] = v2f{0.f, 0.f}; acc[r][1] = v2f{0.f, 0.f}; }

#pragma unroll 2
            for (int k = 0; k < 80; ++k) {
                const v2f* wv = (const v2f*)&wT[k][4 * gi];
                v2f w01 = wv[0], w23 = wv[1];
                float4 x03 = *(const float4*)&xT[k][4 * tj];
                v2f xp0 = {x03.x, x03.y}, xp1 = {x03.z, x03.w};
                float wr[4] = {w01.x, w01.y, w23.x, w23.y};
#pragma unroll
                for (int r = 0; r < 4; ++r) {
                    v2f ws = {wr[r], wr[r]};
                    acc[r][0] = pkfma(ws, xp0, acc[r][0]);
                    acc[r][1] = pkfma(ws, xp1, acc[r][1]);
                }
            }
            __syncthreads();

            float (*ot)[NTT + 4] = (float (*)[NTT + 4])xT;
#pragma unroll
            for (int r = 0; r < 4; ++r) {
                float bias = bias_s[4 * gi + r];
                float2 o0, o1;
                o0.x = acc[r][0].x + bias; o0.y = acc[r][0].y + bias;
                o1.x = acc[r][1].x + bias; o1.y = acc[r][1].y + bias;
                *(float2*)&ot[4 * gi + r][4 * tj]     = o0;
                *(float2*)&ot[4 * gi + r][4 * tj + 2] = o1;
            }
            __syncthreads();

            for (int i = tid; i < GT * (NTT / 4); i += 512) {
                int row = i >> 5;
                int col = i & 31;
                int t = tt0 + 4 * col;
                if (t < ct) {
                    float4 v = *(const float4*)&ot[row][4 * col];
                    *(float4*)(raw_gm + ((size_t)b * G + g0b + row) * ct + t) = v;
                }
            }
        }
        (void)ti;
    }
}

extern "C" void kernel_launch(void* const* d_in, const int* in_sizes, int n_in,
                              void* d_out, int out_size, void* d_ws, size_t ws_size,
                              hipStream_t stream) {
    (void)in_sizes; (void)n_in; (void)out_size;
    const float* x      = (const float*)d_in[0];
    const float* w_ih_f = (const float*)d_in[1];
    const float* w_hh_f = (const float*)d_in[2];
    const float* b_ih_f = (const float*)d_in[3];
    const float* b_hh_f = (const float*)d_in[4];
    const float* w_ih_b = (const float*)d_in[5];
    const float* w_hh_b = (const float*)d_in[6];
    const float* b_ih_b = (const float*)d_in[7];
    const float* b_hh_b = (const float*)d_in[8];
    const float* w1     = (const float*)d_in[9];
    const float* b1     = (const float*)d_in[10];
    const float* w2     = (const float*)d_in[11];
    const float* b2     = (const float*)d_in[12];
    (void)w_hh_b;
    float* out = (float*)d_out;

    float* h_state = (float*)d_ws;
    unsigned short* wfrag = (unsigned short*)(h_state + B * H);
    float* base = (float*)((char*)wfrag + 196608);
    size_t used = (size_t)B * H * 4 + 196608;
    size_t avail = ws_size > used ? ws_size - used : 0;

    size_t per = (size_t)B * G;                    // floats per timestep
    long long chunk = 376;
    if (avail < 4 * per * 4 * (size_t)chunk) {
        long long c = (long long)(avail / (4 * per * 4)) & ~3LL;
        chunk = c;
    }
    if (chunk > T) chunk = T;
    if (chunk < 4) chunk = 4;
    int nc = (int)((T + chunk - 1) / chunk);

    float* raw[2] = { base, base + per * chunk };
    float* gx3[2] = { base + 2 * per * chunk, base + 3 * per * chunk };

    auto ctOf = [&](int ci) -> int {
        if (ci < 0 || ci >= nc) return 0;
        long long t0 = (long long)ci * chunk;
        long long r = T - t0;
        return (int)((r < chunk) ? r : chunk);
    };

    wfrag_kernel<<<dim3(24), dim3(256), 0, stream>>>(w_hh_f, wfrag);

    // D-2: pure gemm chunk0
    fused_kernel<<<dim3(256), dim3(512), 0, stream>>>(
        x, w_ih_f, b_ih_f,
        nullptr, 0, 0, 0,
        nullptr, nullptr, 0,
        raw[0], 0, ctOf(0),
        wfrag, b_hh_f, h_state,
        w_ih_b, b_ih_b, b_hh_b, w1, b1, w2, b2, out);
    // D-1: repack chunk0 + gemm chunk1
    fused_kernel<<<dim3(256), dim3(512), 0, stream>>>(
        x, w_ih_f, b_ih_f,
        nullptr, 0, 0, 0,
        raw[0], gx3[0], ctOf(0),
        raw[1], (int)chunk, ctOf(1),
        wfrag, b_hh_f, h_state,
        w_ih_b, b_ih_b, b_hh_b, w1, b1, w2, b2, out);
    // Di: scan i + repack i+1 + gemm i+2
    for (int i = 0; i < nc; ++i) {
        fused_kernel<<<dim3(256), dim3(512), 0, stream>>>(
            x, w_ih_f, b_ih_f,
            gx3[i & 1], ctOf(i), (i == 0) ? 1 : 0, (i == nc - 1) ? 1 : 0,
            raw[(i + 1) & 1], gx3[(i + 1) & 1], ctOf(i + 1),
            raw[i & 1], (int)((long long)(i + 2) * chunk), ctOf(i + 2),
            wfrag, b_hh_f, h_state,
            w_ih_b, b_ih_b, b_hh_b, w1, b1, w2, b2, out);
    }
}